// Round 5
// baseline (136.889 us; speedup 1.0000x reference)
//
#include <hip/hip_runtime.h>

// Tucker scoring: out[n] = sum_{p,q,r} U[i_n,p] V[j_n,q] W[k_n,r] G[p,q,r]
// P=Q=R=32, N=131072, num_time=5000.
//
// Round 5 pipeline (3 dispatches):
//   1. memset counts (20 KB)
//   2. scatter_build: heterogeneous kernel — blocks [0,SB) bin samples by k
//      into fixed-CAP bins with packed {n,i,j,k} records; blocks [SB,..)
//      build H[k][p][q] = sum_r G[p,q,r] W[k,r] (independent work, one launch)
//   3. tucker_eval_grouped: wave per k (4 k/block), H[k] staged to 4 KB LDS,
//      8 lanes x 8 concurrent samples per wave iteration (branch-free full
//      groups + tail), conflict-free b128 LDS broadcasts, 3 shfl_xor reduce;
//      overflow spill list handled in a grid-stride tail (empty in practice).

#define BIN_CAP 128

// ---------------------------------------------------------------------------
// scatter_build: blocks [0, n_scatter_blocks) scatter; the rest build H.
// ---------------------------------------------------------------------------
__global__ __launch_bounds__(256) void scatter_build(
        const int* __restrict__ K, const int* __restrict__ I,
        const int* __restrict__ J, const float* __restrict__ G,
        const float* __restrict__ W, int* __restrict__ counts,
        int4* __restrict__ bins, int* __restrict__ ovf_cnt,
        int4* __restrict__ ovf, float* __restrict__ H,
        int n, int num_time, int n_scatter_blocks) {
    if ((int)blockIdx.x < n_scatter_blocks) {
        // ------------------ scatter role ------------------
        const int idx = blockIdx.x * 256 + threadIdx.x;
        if (idx < n) {
            int k = K[idx];
            int4 rec = make_int4(idx, I[idx], J[idx], k);
            int pos = atomicAdd(&counts[k], 1);
            if (pos < BIN_CAP) {
                bins[(size_t)k * BIN_CAP + pos] = rec;
            } else {
                int o = atomicAdd(ovf_cnt, 1);
                ovf[o] = rec;
            }
        }
    } else {
        // ------------------ build-H role ------------------
        const int pq4 = threadIdx.x;            // owns pq in [4*pq4, 4*pq4+4)
        const int kbase = ((int)blockIdx.x - n_scatter_blocks) * 8;

        float acc[8][4];
#pragma unroll
        for (int kk = 0; kk < 8; ++kk)
#pragma unroll
            for (int i = 0; i < 4; ++i) acc[kk][i] = 0.f;

#pragma unroll
        for (int r4 = 0; r4 < 8; ++r4) {
            float4 g[4];
#pragma unroll
            for (int i = 0; i < 4; ++i)
                g[i] = *(const float4*)(G + (size_t)(pq4 * 4 + i) * 32 + r4 * 4);
#pragma unroll
            for (int kk = 0; kk < 8; ++kk) {
                int k = kbase + kk;
                int kc = (k < num_time) ? k : (num_time - 1);
                float4 w = *(const float4*)(W + (size_t)kc * 32 + r4 * 4);
#pragma unroll
                for (int i = 0; i < 4; ++i)
                    acc[kk][i] += g[i].x * w.x + g[i].y * w.y +
                                  g[i].z * w.z + g[i].w * w.w;
            }
        }

#pragma unroll
        for (int kk = 0; kk < 8; ++kk) {
            int k = kbase + kk;
            if (k < num_time) {
                float4 o = make_float4(acc[kk][0], acc[kk][1], acc[kk][2], acc[kk][3]);
                *(float4*)(H + (size_t)k * 1024 + pq4 * 4) = o;
            }
        }
    }
}

// ---------------------------------------------------------------------------
// eval: 256-thread block = 4 waves; wave w owns k = 4*blockIdx + w.
// H[k] (4KB) staged to LDS per wave. Lane = s8*8 + qq. 8 samples concurrently
// per wave iteration; branch-free over full groups, then one partial tail.
// After the bin loop, all waves grid-stride the overflow list (normally 0).
// ---------------------------------------------------------------------------
__global__ __launch_bounds__(256) void tucker_eval_grouped(
        const float* __restrict__ U, const float* __restrict__ V,
        const float* __restrict__ H, const int* __restrict__ counts,
        const int4* __restrict__ bins, const int* __restrict__ ovf_cnt,
        const int4* __restrict__ ovf, float* __restrict__ out,
        int num_time) {
    __shared__ float4 Hs4[4][256];           // 16 KB: one H row per wave
    const int wave = threadIdx.x >> 6;
    const int lane = threadIdx.x & 63;
    const int k = blockIdx.x * 4 + wave;
    const int qq = lane & 7;                 // q-quad
    const int s8 = lane >> 3;                // sample slot within iteration

    int m = 0;
    if (k < num_time) {
        const float4* __restrict__ Hrow4 = (const float4*)(H + (size_t)k * 1024);
#pragma unroll
        for (int c = 0; c < 4; ++c)
            Hs4[wave][lane + 64 * c] = Hrow4[lane + 64 * c];
        m = counts[k];
        m = (m < BIN_CAP) ? m : BIN_CAP;
    }
    __syncthreads();

    if (k < num_time && m > 0) {
        const float4* __restrict__ Hw = Hs4[wave];
        const int4* __restrict__ binsk = bins + (size_t)k * BIN_CAP;
        const int full = m >> 3;

        for (int t = 0; t < full; ++t) {
            const int s = t * 8 + s8;
            int4 rec = binsk[s];
            const float4* __restrict__ Ur = (const float4*)(U + (size_t)rec.y * 32);
            float4 u[8];
#pragma unroll
            for (int p4 = 0; p4 < 8; ++p4) u[p4] = Ur[p4];
            float4 v4 = ((const float4*)(V + (size_t)rec.z * 32))[qq];

            float4 acc = make_float4(0.f, 0.f, 0.f, 0.f);
#pragma unroll
            for (int p4 = 0; p4 < 8; ++p4) {
                float4 h;
                h = Hw[(p4 * 4 + 0) * 8 + qq];
                acc.x += u[p4].x * h.x; acc.y += u[p4].x * h.y;
                acc.z += u[p4].x * h.z; acc.w += u[p4].x * h.w;
                h = Hw[(p4 * 4 + 1) * 8 + qq];
                acc.x += u[p4].y * h.x; acc.y += u[p4].y * h.y;
                acc.z += u[p4].y * h.z; acc.w += u[p4].y * h.w;
                h = Hw[(p4 * 4 + 2) * 8 + qq];
                acc.x += u[p4].z * h.x; acc.y += u[p4].z * h.y;
                acc.z += u[p4].z * h.z; acc.w += u[p4].z * h.w;
                h = Hw[(p4 * 4 + 3) * 8 + qq];
                acc.x += u[p4].w * h.x; acc.y += u[p4].w * h.y;
                acc.z += u[p4].w * h.z; acc.w += u[p4].w * h.w;
            }
            float sd = acc.x * v4.x + acc.y * v4.y + acc.z * v4.z + acc.w * v4.w;
            sd += __shfl_xor(sd, 1, 64);
            sd += __shfl_xor(sd, 2, 64);
            sd += __shfl_xor(sd, 4, 64);
            if (qq == 0) out[rec.x] = sd;
        }

        // partial tail group
        const int s = full * 8 + s8;
        if (s < m) {
            int4 rec = binsk[s];
            const float4* __restrict__ Ur = (const float4*)(U + (size_t)rec.y * 32);
            float4 u[8];
#pragma unroll
            for (int p4 = 0; p4 < 8; ++p4) u[p4] = Ur[p4];
            float4 v4 = ((const float4*)(V + (size_t)rec.z * 32))[qq];

            float4 acc = make_float4(0.f, 0.f, 0.f, 0.f);
#pragma unroll
            for (int p4 = 0; p4 < 8; ++p4) {
                float4 h;
                h = Hw[(p4 * 4 + 0) * 8 + qq];
                acc.x += u[p4].x * h.x; acc.y += u[p4].x * h.y;
                acc.z += u[p4].x * h.z; acc.w += u[p4].x * h.w;
                h = Hw[(p4 * 4 + 1) * 8 + qq];
                acc.x += u[p4].y * h.x; acc.y += u[p4].y * h.y;
                acc.z += u[p4].y * h.z; acc.w += u[p4].y * h.w;
                h = Hw[(p4 * 4 + 2) * 8 + qq];
                acc.x += u[p4].z * h.x; acc.y += u[p4].z * h.y;
                acc.z += u[p4].z * h.z; acc.w += u[p4].z * h.w;
                h = Hw[(p4 * 4 + 3) * 8 + qq];
                acc.x += u[p4].w * h.x; acc.y += u[p4].w * h.y;
                acc.z += u[p4].w * h.z; acc.w += u[p4].w * h.w;
            }
            float sd = acc.x * v4.x + acc.y * v4.y + acc.z * v4.z + acc.w * v4.w;
            sd += __shfl_xor(sd, 1, 64);
            sd += __shfl_xor(sd, 2, 64);
            sd += __shfl_xor(sd, 4, 64);
            if (qq == 0) out[rec.x] = sd;
        }
    }

    // ---------------- overflow spill tail (normally empty) ----------------
    const int cnt = *ovf_cnt;
    if (cnt > 0) {
        const int pg = lane >> 3;
        const int gwave = blockIdx.x * 4 + wave;
        const int nwaves = gridDim.x * 4;
        for (int s = gwave; s < cnt; s += nwaves) {
            int4 rec = ovf[s];
            const float4* __restrict__ Hrow = (const float4*)(H + (size_t)rec.w * 1024);
            const float* __restrict__ Ur = U + (size_t)rec.y * 32;

            float4 acc = make_float4(0.f, 0.f, 0.f, 0.f);
#pragma unroll
            for (int it = 0; it < 4; ++it) {
                float4 h = Hrow[lane + it * 64];
                float up = Ur[pg + it * 8];
                acc.x += up * h.x; acc.y += up * h.y;
                acc.z += up * h.z; acc.w += up * h.w;
            }
#pragma unroll
            for (int off = 8; off < 64; off <<= 1) {
                acc.x += __shfl_xor(acc.x, off, 64);
                acc.y += __shfl_xor(acc.y, off, 64);
                acc.z += __shfl_xor(acc.z, off, 64);
                acc.w += __shfl_xor(acc.w, off, 64);
            }
            float4 v4 = ((const float4*)(V + (size_t)rec.z * 32))[qq];
            float sd = acc.x * v4.x + acc.y * v4.y + acc.z * v4.z + acc.w * v4.w;
            sd += __shfl_xor(sd, 1, 64);
            sd += __shfl_xor(sd, 2, 64);
            sd += __shfl_xor(sd, 4, 64);
            if (lane == 0) out[rec.x] = sd;
        }
    }
}

// ---------------------------------------------------------------------------
// Fallbacks for small workspace
// ---------------------------------------------------------------------------
__global__ __launch_bounds__(256) void build_H(const float* __restrict__ G,
                                               const float* __restrict__ W,
                                               float* __restrict__ H,
                                               int num_time) {
    const int pq4 = threadIdx.x;
    const int kbase = blockIdx.x * 8;
    float acc[8][4];
#pragma unroll
    for (int kk = 0; kk < 8; ++kk)
#pragma unroll
        for (int i = 0; i < 4; ++i) acc[kk][i] = 0.f;
#pragma unroll
    for (int r4 = 0; r4 < 8; ++r4) {
        float4 g[4];
#pragma unroll
        for (int i = 0; i < 4; ++i)
            g[i] = *(const float4*)(G + (size_t)(pq4 * 4 + i) * 32 + r4 * 4);
#pragma unroll
        for (int kk = 0; kk < 8; ++kk) {
            int k = kbase + kk;
            int kc = (k < num_time) ? k : (num_time - 1);
            float4 w = *(const float4*)(W + (size_t)kc * 32 + r4 * 4);
#pragma unroll
            for (int i = 0; i < 4; ++i)
                acc[kk][i] += g[i].x * w.x + g[i].y * w.y + g[i].z * w.z + g[i].w * w.w;
        }
    }
#pragma unroll
    for (int kk = 0; kk < 8; ++kk) {
        int k = kbase + kk;
        if (k < num_time) {
            float4 o = make_float4(acc[kk][0], acc[kk][1], acc[kk][2], acc[kk][3]);
            *(float4*)(H + (size_t)k * 1024 + pq4 * 4) = o;
        }
    }
}

__global__ __launch_bounds__(256) void tucker_eval(const int* __restrict__ I,
                                                   const int* __restrict__ J,
                                                   const int* __restrict__ K,
                                                   const float* __restrict__ U,
                                                   const float* __restrict__ V,
                                                   const float* __restrict__ H,
                                                   float* __restrict__ out,
                                                   int n_samples) {
    const int wave = (int)((blockIdx.x * (unsigned)blockDim.x + threadIdx.x) >> 6);
    const int lane = threadIdx.x & 63;
    if (wave >= n_samples) return;
    const int i = I[wave];
    const int j = J[wave];
    const int k = K[wave];
    const int qq = lane & 7;
    const int pg = lane >> 3;
    const float4* __restrict__ Hrow = (const float4*)(H + (size_t)k * 1024);
    const float* __restrict__ Urow = U + (size_t)i * 32;
    float4 acc = make_float4(0.f, 0.f, 0.f, 0.f);
#pragma unroll
    for (int it = 0; it < 4; ++it) {
        float4 h = Hrow[lane + it * 64];
        float up = Urow[pg + it * 8];
        acc.x += up * h.x; acc.y += up * h.y;
        acc.z += up * h.z; acc.w += up * h.w;
    }
#pragma unroll
    for (int off = 8; off < 64; off <<= 1) {
        acc.x += __shfl_xor(acc.x, off, 64);
        acc.y += __shfl_xor(acc.y, off, 64);
        acc.z += __shfl_xor(acc.z, off, 64);
        acc.w += __shfl_xor(acc.w, off, 64);
    }
    float4 v4 = ((const float4*)(V + (size_t)j * 32))[qq];
    float s = acc.x * v4.x + acc.y * v4.y + acc.z * v4.z + acc.w * v4.w;
    s += __shfl_xor(s, 1, 64);
    s += __shfl_xor(s, 2, 64);
    s += __shfl_xor(s, 4, 64);
    if (lane == 0) out[wave] = s;
}

__global__ __launch_bounds__(256) void tucker_direct(const int* __restrict__ I,
                                                     const int* __restrict__ J,
                                                     const int* __restrict__ K,
                                                     const float* __restrict__ U,
                                                     const float* __restrict__ V,
                                                     const float* __restrict__ W,
                                                     const float* __restrict__ G,
                                                     float* __restrict__ out,
                                                     int n_samples) {
    __shared__ float Gc[4 * 32 * 32];
    const int n = blockIdx.x * blockDim.x + threadIdx.x;
    const bool active = (n < n_samples);
    int i = 0, j = 0, k = 0;
    if (active) { i = I[n]; j = J[n]; k = K[n]; }
    float4 w4[8];
#pragma unroll
    for (int r4 = 0; r4 < 8; ++r4)
        w4[r4] = ((const float4*)(W + (size_t)k * 32))[r4];
    float v[32];
#pragma unroll
    for (int q4 = 0; q4 < 8; ++q4) {
        float4 t = ((const float4*)(V + (size_t)j * 32))[q4];
        v[q4 * 4 + 0] = t.x; v[q4 * 4 + 1] = t.y;
        v[q4 * 4 + 2] = t.z; v[q4 * 4 + 3] = t.w;
    }
    const float* __restrict__ Urow = U + (size_t)i * 32;
    float acc = 0.f;
    for (int c = 0; c < 8; ++c) {
        __syncthreads();
#pragma unroll
        for (int t = 0; t < 4; ++t) {
            int idx = threadIdx.x + t * 256;
            ((float4*)Gc)[idx] = ((const float4*)(G + (size_t)c * 4096))[idx];
        }
        __syncthreads();
        for (int pp = 0; pp < 4; ++pp) {
            float up = Urow[c * 4 + pp];
#pragma unroll
            for (int q = 0; q < 32; ++q) {
                float t0 = 0.f;
#pragma unroll
                for (int r4 = 0; r4 < 8; ++r4) {
                    float4 g = ((const float4*)Gc)[pp * 256 + q * 8 + r4];
                    t0 += g.x * w4[r4].x + g.y * w4[r4].y + g.z * w4[r4].z + g.w * w4[r4].w;
                }
                acc += up * v[q] * t0;
            }
        }
    }
    if (active) out[n] = acc;
}

extern "C" void kernel_launch(void* const* d_in, const int* in_sizes, int n_in,
                              void* d_out, int out_size, void* d_ws, size_t ws_size,
                              hipStream_t stream) {
    const int*   I = (const int*)d_in[0];
    const int*   J = (const int*)d_in[1];
    const int*   K = (const int*)d_in[2];
    const float* U = (const float*)d_in[3];   // [NUM_USER, 32]
    const float* V = (const float*)d_in[4];   // [NUM_ITEM, 32]
    const float* W = (const float*)d_in[5];   // [NUM_TIME, 32]
    const float* G = (const float*)d_in[6];   // [32, 32, 32]
    float* out = (float*)d_out;

    const int n_samples = in_sizes[0];
    const int num_time = in_sizes[5] / 32;

    const size_t h_bytes = (size_t)num_time * 1024 * sizeof(float);
    const size_t z_bytes = (size_t)(num_time + 1) * sizeof(int);   // counts + ovf_cnt
    const size_t z_pad = (z_bytes + 15) & ~(size_t)15;
    const size_t bins_bytes = (size_t)num_time * BIN_CAP * sizeof(int4);
    const size_t ovf_bytes = (size_t)n_samples * sizeof(int4);
    const size_t need_full = h_bytes + z_pad + bins_bytes + ovf_bytes;

    if (ws_size >= need_full) {
        float* H       = (float*)d_ws;
        int*   counts  = (int*)((char*)d_ws + h_bytes);      // num_time
        int*   ovf_cnt = counts + num_time;                  // 1
        int4*  bins    = (int4*)((char*)d_ws + h_bytes + z_pad);
        int4*  ovf     = (int4*)((char*)d_ws + h_bytes + z_pad + bins_bytes);

        const int sb = (n_samples + 255) / 256;              // scatter blocks
        const int bb = (num_time + 7) / 8;                   // build blocks

        hipMemsetAsync(counts, 0, z_bytes, stream);
        scatter_build<<<sb + bb, 256, 0, stream>>>(K, I, J, G, W, counts, bins,
                                                   ovf_cnt, ovf, H, n_samples,
                                                   num_time, sb);
        tucker_eval_grouped<<<(num_time + 3) / 4, 256, 0, stream>>>(
            U, V, H, counts, bins, ovf_cnt, ovf, out, num_time);
    } else if (ws_size >= h_bytes) {
        float* H = (float*)d_ws;
        build_H<<<(num_time + 7) / 8, 256, 0, stream>>>(G, W, H, num_time);
        const long long total_threads = (long long)n_samples * 64;
        tucker_eval<<<(int)((total_threads + 255) / 256), 256, 0, stream>>>(
            I, J, K, U, V, H, out, n_samples);
    } else {
        tucker_direct<<<(n_samples + 255) / 256, 256, 0, stream>>>(
            I, J, K, U, V, W, G, out, n_samples);
    }
}